// Round 3
// baseline (4154.160 us; speedup 1.0000x reference)
//
#include <hip/hip_runtime.h>
#include <math.h>

#define BB 4
#define N0 4096
#define NEWP 1152
#define GD 256
#define HD 128
#define KSEL 64
#define NSTEPS 10
#define NMAX (N0 + NSTEPS*NEWP)   /* 15616 */
#define NNEW (NSTEPS*NEWP)        /* 11520 */

#define NBLK 256
#define NTHR 512

/* ---- workspace layout (float offsets) ---- */
#define OFF_CANVAS 0
#define OFF_MINAB  (OFF_CANVAS + BB*NMAX*3)
#define OFF_MINCD  (OFF_MINAB + 2*BB*N0)
#define OFF_GMAX   (OFF_MINCD + BB*NNEW + BB*N0)
#define OFF_H      (OFF_GMAX + BB*GD)
#define OFF_C      (OFF_H + 2*BB*HD)
#define OFF_ACC    (OFF_C + 2*BB*HD)
#define OFF_CENTER (OFF_ACC + 16)
#define OFF_PART   (OFF_CENTER + 32)
#define OFF_GPRE   (OFF_PART + BB*32*8)      /* 4*512 gate partials */

#define AGT __HIP_MEMORY_SCOPE_AGENT

/* coherent (L1/L2-bypassing, IF-coherence-point) accessors for cross-block
   data. Weights/inputs keep normal cached loads. */
__device__ __forceinline__ float cld(const float* p){
  return __hip_atomic_load((float*)p, __ATOMIC_RELAXED, AGT);
}
__device__ __forceinline__ void cst(float* p, float v){
  __hip_atomic_store(p, v, __ATOMIC_RELAXED, AGT);
}
__device__ __forceinline__ unsigned culd(const unsigned* p){
  return __hip_atomic_load((unsigned*)p, __ATOMIC_RELAXED, AGT);
}
__device__ __forceinline__ void cust(unsigned* p, unsigned v){
  __hip_atomic_store(p, v, __ATOMIC_RELAXED, AGT);
}
__device__ __forceinline__ float ldc(const float* p, bool coh){
  return coh ? cld(p) : *p;
}

__device__ __forceinline__ unsigned enc_f(float f){
  unsigned u = __float_as_uint(f);
  return (u & 0x80000000u) ? ~u : (u | 0x80000000u);
}
__device__ __forceinline__ float dec_f(unsigned e){
  unsigned u = (e & 0x80000000u) ? (e & 0x7fffffffu) : ~e;
  return __uint_as_float(u);
}
__device__ __forceinline__ float sigm(float x){ return 1.f/(1.f+expf(-x)); }

__device__ __forceinline__ float block_sum(float v, volatile float* red){
#pragma unroll
  for (int s=32;s>0;s>>=1) v += __shfl_down(v, s, 64);
  int lane = threadIdx.x & 63, w = threadIdx.x >> 6, nw = blockDim.x >> 6;
  __syncthreads();
  if (lane==0) red[w] = v;
  __syncthreads();
  if (w==0){
    float x = (lane < nw) ? red[lane] : 0.f;
#pragma unroll
    for (int s=8;s>0;s>>=1) x += __shfl_down(x, s, 64);
    if (lane==0) red[0] = x;
  }
  __syncthreads();
  float r = red[0];
  __syncthreads();
  return r;
}
__device__ __forceinline__ float block_max(float v, volatile float* red){
#pragma unroll
  for (int s=32;s>0;s>>=1) v = fmaxf(v, __shfl_down(v, s, 64));
  int lane = threadIdx.x & 63, w = threadIdx.x >> 6, nw = blockDim.x >> 6;
  __syncthreads();
  if (lane==0) red[w] = v;
  __syncthreads();
  if (w==0){
    float x = (lane < nw) ? red[lane] : -3.4e38f;
#pragma unroll
    for (int s=8;s>0;s>>=1) x = fmaxf(x, __shfl_down(x, s, 64));
    if (lane==0) red[0] = x;
  }
  __syncthreads();
  float r = red[0];
  __syncthreads();
  return r;
}

/* ---- fence-free grid barrier: 2-level monotonic arrive/spin (proven r2) ---- */
__device__ __align__(128) unsigned g_grp[256];   /* 8 counters, stride 32 */
__device__ __align__(128) unsigned g_root;
__device__ __align__(128) unsigned g_gen;

__device__ __forceinline__ void gsync(){
  __syncthreads();
  if (threadIdx.x == 0){
    unsigned snap = __hip_atomic_load(&g_gen, __ATOMIC_RELAXED, AGT);
    asm volatile("" ::: "memory");
    int g = blockIdx.x >> 5;
    unsigned od = __hip_atomic_fetch_add(&g_grp[g*32], 1u, __ATOMIC_RELAXED, AGT);
    bool done = false;
    if ((od & 31u) == 31u){
      unsigned rd = __hip_atomic_fetch_add(&g_root, 1u, __ATOMIC_RELAXED, AGT);
      if ((rd & 7u) == 7u){
        __hip_atomic_fetch_add(&g_gen, 1u, __ATOMIC_RELAXED, AGT);
        done = true;
      }
    }
    if (!done){
      while (__hip_atomic_load(&g_gen, __ATOMIC_RELAXED, AGT) == snap)
        __builtin_amdgcn_s_sleep(2);
    }
    asm volatile("" ::: "memory");
  }
  __syncthreads();
}

/* one 16KB shared-memory arena, aliased per phase */
struct alignas(16) SU {
  union {
    struct { float sy0[1024], sy1[1024], sy2[1024], sny[1024]; } ch;
    struct { float sBatt[128]; float sGH[GD+HD]; float red[16]; } sl;
    struct { float red[16]; float sC[3]; unsigned cbufA[2][8]; unsigned cbufB[2][8];
             int tieCnt; int tieIdx[256]; } sa;
    struct { float sG[512]; float sH[HD]; float sRf[HD]; } re;
    struct { float red[16]; } rd;
  } u;
};

/* fused enc1->enc2->enc3 for one point, NC 16-wide d-chunks at d0.
   f2 computed in two 64-register halves (kh split) to cap VGPR pressure.
   Summation orders match the reference implementation exactly. */
template<int NC>
__device__ __forceinline__ void enc123_point(
    float p0, float p1, float p2, int d0,
    const float* __restrict__ w1, const float* __restrict__ b1,
    const float* __restrict__ w2, const float* __restrict__ b2,
    const float* __restrict__ w3, const float* __restrict__ b3,
    bool act, unsigned* gmaxrow, int tid)
{
  float f1[64];
#pragma unroll
  for (int j=0;j<64;j++)
    f1[j] = fmaxf(0.f, b1[j] + p0*w1[j] + p1*w1[64+j] + p2*w1[128+j]);
  float accd[NC][16];
#pragma unroll
  for (int c=0;c<NC;c++)
#pragma unroll
    for (int d=0;d<16;d++) accd[c][d] = b3[d0 + c*16 + d];
#pragma unroll
  for (int kh=0; kh<2; kh++){
    float f2h[64];
#pragma unroll
    for (int k2=0;k2<64;k2++){
      int k = kh*64 + k2;
      float s = b2[k];
#pragma unroll
      for (int j=0;j<64;j++) s = fmaf(f1[j], w2[j*128+k], s);
      f2h[k2] = fmaxf(s, 0.f);
    }
#pragma unroll
    for (int k2=0;k2<64;k2++){
      const float* wr = w3 + (size_t)(kh*64+k2)*256 + d0;
      float fv = f2h[k2];
#pragma unroll
      for (int c=0;c<NC;c++)
#pragma unroll
        for (int d=0;d<16;d++) accd[c][d] = fmaf(fv, wr[c*16+d], accd[c][d]);
    }
  }
#pragma unroll
  for (int c=0;c<NC;c++)
#pragma unroll
    for (int d=0;d<16;d++){
      float v = act ? accd[c][d] : -3.4e38f;
#pragma unroll
      for (int s2=32;s2>0;s2>>=1) v = fmaxf(v, __shfl_down(v, s2, 64));
      if ((tid & 63) == 0) atomicMax(&gmaxrow[d0 + c*16 + d], enc_f(v));
    }
}

/* one chamfer tile: min over a staged Y slab [tn pts] for QN X-chunks */
template<int QN>
__device__ __forceinline__ void chamfer_tile(
    const float* X, const float* Y, unsigned* mp,
    int Nx, int xbase, int tn, bool xcv, bool ycv,
    float* sy0, float* sy1, float* sy2, float* sny, int tid)
{
  for (int tt=tid; tt<tn; tt+=NTHR){
    const float* yp = Y + (size_t)tt*3;
    float y0=ldc(yp,ycv), y1=ldc(yp+1,ycv), y2=ldc(yp+2,ycv);
    sy0[tt]=-2.f*y0; sy1[tt]=-2.f*y1; sy2[tt]=-2.f*y2;
    sny[tt]=y0*y0+y1*y1+y2*y2;
  }
  __syncthreads();
  float X0[QN],X1[QN],X2[QN],NXr[QN],MN[QN]; int XI[QN]; bool VA[QN];
#pragma unroll
  for (int q=0;q<QN;q++){
    int x = xbase + q*NTHR + tid;
    VA[q] = x < Nx;
    int xc = VA[q] ? x : 0;
    const float* xp = X + (size_t)xc*3;
    X0[q]=ldc(xp,xcv); X1[q]=ldc(xp+1,xcv); X2[q]=ldc(xp+2,xcv);
    NXr[q] = X0[q]*X0[q] + X1[q]*X1[q] + X2[q]*X2[q];
    MN[q] = 3.4e38f; XI[q] = xc;
  }
  const float4* v0 = (const float4*)sy0;
  const float4* v1 = (const float4*)sy1;
  const float4* v2 = (const float4*)sy2;
  const float4* vn = (const float4*)sny;
  int j4n = tn >> 2;
  for (int j=0;j<j4n;j++){
    float4 a0 = v0[j], a1 = v1[j], a2 = v2[j], an = vn[j];
#pragma unroll
    for (int e=0;e<4;e++){
      float y0 = ((const float*)&a0)[e];
      float y1 = ((const float*)&a1)[e];
      float y2 = ((const float*)&a2)[e];
      float ny = ((const float*)&an)[e];
#pragma unroll
      for (int q=0;q<QN;q++){
        float d = fmaf(X0[q], y0, fmaf(X1[q], y1, fmaf(X2[q], y2, ny)));
        MN[q] = fminf(MN[q], d);
      }
    }
  }
  for (int j=j4n*4; j<tn; j++){
    float y0=sy0[j], y1=sy1[j], y2=sy2[j], ny=sny[j];
#pragma unroll
    for (int q=0;q<QN;q++){
      float d = fmaf(X0[q], y0, fmaf(X1[q], y1, fmaf(X2[q], y2, ny)));
      MN[q] = fminf(MN[q], d);
    }
  }
#pragma unroll
  for (int q=0;q<QN;q++)
    if (VA[q]) atomicMin(&mp[XI[q]], enc_f(MN[q] + NXr[q]));
}

__global__ __attribute__((amdgpu_flat_work_group_size(NTHR,NTHR), amdgpu_waves_per_eu(2,2)))
void mega_kernel(
    const float* __restrict__ points, const float* __restrict__ gt,
    const float* __restrict__ w1,  const float* __restrict__ b1,
    const float* __restrict__ w2,  const float* __restrict__ b2,
    const float* __restrict__ w3,  const float* __restrict__ b3,
    const float* __restrict__ aw1, const float* __restrict__ ab1,
    const float* __restrict__ aw2, const float* __restrict__ ab2,
    const float* __restrict__ wih, const float* __restrict__ whh,
    const float* __restrict__ bih, const float* __restrict__ bhh,
    const float* __restrict__ rw1, const float* __restrict__ rb1,
    const float* __restrict__ rw2, const float* __restrict__ rb2,
    float* __restrict__ out, float* __restrict__ ws)
{
  __shared__ SU su;
  const int tid = threadIdx.x;
  const int blk = blockIdx.x;

  float* canvas   = ws + OFF_CANVAS;
  unsigned* minAB = (unsigned*)(ws + OFF_MINAB);
  unsigned* minCD = (unsigned*)(ws + OFF_MINCD);
  unsigned* gmax  = (unsigned*)(ws + OFF_GMAX);
  float* hb       = ws + OFF_H;
  float* cb       = ws + OFF_C;
  float* acc      = ws + OFF_ACC;
  float* centerb  = ws + OFF_CENTER;
  float* partb    = ws + OFF_PART;
  float* gpre     = ws + OFF_GPRE;

  /* ============ P0: init ============ */
  {
    int gid = blk*NTHR + tid;
    if (gid < BB*N0*3){
      int b = gid/(N0*3), r = gid - b*(N0*3);
      cst(&canvas[(size_t)b*NMAX*3 + r], points[gid]);
    }
    if (gid < 2*BB*N0) cust(&minAB[gid], 0xFFFFFFFFu);
    if (gid < BB*NNEW + BB*N0) cust(&minCD[gid], 0xFFFFFFFFu);
    if (gid < BB*GD) cust(&gmax[gid], 0u);
    if (gid < 2*BB*HD){ cst(&hb[gid], 0.f); cst(&cb[gid], 0.f); }
  }
  gsync();

  /* ============ P1: fused enc123 + max-pool of the 16384 initial points.
     256 blocks = 32 point-groups x 8 d-groups (32 dims each). Points read
     from the cached input; NO intermediate feature buffer. ============ */
  {
    int ptg = blk >> 3, dcg = blk & 7;
    int gp = ptg*NTHR + tid;           /* 0..16383 */
    int b  = gp >> 12;
    const float* p = points + (size_t)gp*3;
    float p0 = p[0], p1 = p[1], p2 = p[2];
    enc123_point<2>(p0, p1, p2, dcg*32, w1, b1, w2, b2, w3, b3,
                    true, &gmax[b*GD], tid);
  }
  gsync();

  /* ============ 10-step loop ============ */
  for (int t=0; t<NSTEPS; t++){
    int N   = N0 + t*NEWP;
    int nch = (N + 511) >> 9;
    float* h_in  = hb + (t&1)*BB*HD;
    float* h_out = hb + ((t+1)&1)*BB*HD;
    float* c_in  = cb + (t&1)*BB*HD;
    float* c_out = cb + ((t+1)&1)*BB*HD;

    /* ---- SL phase: attention partials (blocks 0..4nch-1)
            + LSTM gate precompute (blocks 252..255, one per b) ---- */
    if (blk < 4*nch){
      int b = blk / nch, ch = blk - b*nch;
      if (tid < GD+HD)
        su.u.sl.sGH[tid] = (tid < GD) ? dec_f(culd(&gmax[b*GD + tid]))
                                      : cld(&h_in[b*HD + (tid-GD)]);
      __syncthreads();
      if (tid < 128){
        float a = ab1[tid];
        for (int k=0;k<GD+HD;k++) a += su.u.sl.sGH[k] * aw1[(3+k)*128 + tid];
        su.u.sl.sBatt[tid] = a;
      }
      __syncthreads();
      int i = ch*512 + tid;
      bool act = i < N;
      float p0=0.f,p1=0.f,p2=0.f,s=-3.4e38f;
      if (act){
        const float* pp = canvas + (size_t)(b*NMAX + i)*3;
        p0=cld(pp); p1=cld(pp+1); p2=cld(pp+2);
        s = ab2[0];
        for (int j=0;j<128;j++){
          float v = su.u.sl.sBatt[j] + p0*aw1[j] + p1*aw1[128+j] + p2*aw1[256+j];
          s += fmaxf(v, 0.f)*aw2[j];
        }
      }
      float mb = block_max(s, su.u.sl.red);
      float e = act ? expf(s - mb) : 0.f;
      float se = block_sum(e, su.u.sl.red);
      float wx = block_sum(e*p0, su.u.sl.red);
      float wy = block_sum(e*p1, su.u.sl.red);
      float wz = block_sum(e*p2, su.u.sl.red);
      if (tid==0){
        float* pr = partb + (size_t)(b*32 + ch)*8;
        cst(pr+0, mb); cst(pr+1, se); cst(pr+2, wx); cst(pr+3, wy); cst(pr+4, wz);
      }
    } else if (blk >= 252){
      int b = blk - 252;
      if (tid < GD+HD)
        su.u.sl.sGH[tid] = (tid < GD) ? dec_f(culd(&gmax[b*GD + tid]))
                                      : cld(&h_in[b*HD + (tid-GD)]);
      __syncthreads();
      int o = tid;
      float g = bih[o] + bhh[o];
      for (int k=0;k<GD;k++)  g += su.u.sl.sGH[k]    * wih[(size_t)k*512 + o];
      for (int k=0;k<HD;k++)  g += su.u.sl.sGH[GD+k] * whh[(size_t)k*512 + o];
      cst(&gpre[b*512 + o], g);
    }
    gsync();

    /* ---- stepA phase: center+top-K (blocks 0..3)
            + incremental chamfer in otherwise-idle blocks ---- */
    if (blk < 4){
      int b = blk;
      const float* cv = canvas + (size_t)b*NMAX*3;
      int lane = tid & 63, wid = tid >> 6;

      float pm=-3.4e38f, pse=0.f, pwx=0.f, pwy=0.f, pwz=0.f;
      if (tid < nch){
        const float* pp = partb + (size_t)(b*32 + tid)*8;
        pm=cld(pp); pse=cld(pp+1); pwx=cld(pp+2); pwy=cld(pp+3); pwz=cld(pp+4);
      }
      float M = block_max(pm, su.u.sa.red);
      float w = (tid < nch) ? expf(pm - M) : 0.f;
      float se = block_sum(pse*w, su.u.sa.red);
      float wx = block_sum(pwx*w, su.u.sa.red);
      float wy = block_sum(pwy*w, su.u.sa.red);
      float wz = block_sum(pwz*w, su.u.sa.red);
      if (tid==0){ su.u.sa.sC[0]=wx/se; su.u.sa.sC[1]=wy/se; su.u.sa.sC[2]=wz/se; }
      __syncthreads();
      float cx=su.u.sa.sC[0], cy=su.u.sa.sC[1], cz=su.u.sa.sC[2];
      if (tid<3) cst(&centerb[b*3+tid], su.u.sa.sC[tid]);

      unsigned ur[32];
#pragma unroll
      for (int q=0;q<32;q+=4){
        float px[4], py[4], pz[4];
#pragma unroll
        for (int r=0;r<4;r++){
          int i = tid + (q+r)*NTHR;
          int ic2 = (i < N) ? i : 0;
          const float* p = cv + (size_t)ic2*3;
          px[r]=cld(p); py[r]=cld(p+1); pz[r]=cld(p+2);
        }
#pragma unroll
        for (int r=0;r<4;r++){
          int i = tid + (q+r)*NTHR;
          ur[q+r] = 0xFFFFFFFFu;
          if (i < N){
            float dx=px[r]-cx, dy=py[r]-cy, dz=pz[r]-cz;
            ur[q+r] = __float_as_uint(dx*dx + dy*dy + dz*dz);
          }
        }
      }

      unsigned T = 0u;
      int cntBelow = 0;
      int par = 0;
      {
        unsigned cand = 1u<<30;
        unsigned tc = 0;
#pragma unroll
        for (int q=0;q<32;q++) tc += (ur[q] < cand) ? 1u : 0u;
#pragma unroll
        for (int s2=32;s2>0;s2>>=1) tc += __shfl_down(tc, s2, 64);
        if (lane==0) su.u.sa.cbufA[par][wid] = tc;
        __syncthreads();
        unsigned tot = 0;
#pragma unroll
        for (int i2=0;i2<8;i2++) tot += su.u.sa.cbufA[par][i2];
        if ((int)tot < KSEL){ T = cand; cntBelow = (int)tot; }
        par ^= 1;
      }
      for (int bit=29; bit>=1; bit-=2){
        unsigned q1 = 1u<<(bit-1);
        unsigned c1 = T + q1, c2 = T + 2u*q1, c3 = T + 3u*q1;
        unsigned ta = 0, tb = 0;
#pragma unroll
        for (int q=0;q<32;q++){
          unsigned u = ur[q];
          ta += (u < c1 ? 1u : 0u) | (u < c2 ? 0x10000u : 0u);
          tb += (u < c3 ? 1u : 0u);
        }
#pragma unroll
        for (int s2=32;s2>0;s2>>=1){ ta += __shfl_down(ta, s2, 64); tb += __shfl_down(tb, s2, 64); }
        if (lane==0){ su.u.sa.cbufA[par][wid] = ta; su.u.sa.cbufB[par][wid] = tb; }
        __syncthreads();
        unsigned sa2 = 0, sb2 = 0;
#pragma unroll
        for (int i2=0;i2<8;i2++){ sa2 += su.u.sa.cbufA[par][i2]; sb2 += su.u.sa.cbufB[par][i2]; }
        int n1 = (int)(sa2 & 0xFFFFu), n2 = (int)(sa2 >> 16), n3 = (int)sb2;
        if (n3 < KSEL){ T = c3; cntBelow = n3; }
        else if (n2 < KSEL){ T = c2; cntBelow = n2; }
        else if (n1 < KSEL){ T = c1; cntBelow = n1; }
        par ^= 1;
      }
      int kneed = KSEL - cntBelow;

      if (tid==0) su.u.sa.tieCnt = 0;
      __syncthreads();
      float sx=0.f, sy=0.f, sz=0.f;
#pragma unroll
      for (int q=0;q<32;q++){
        unsigned uu = ur[q];
        if (uu < T){
          const float* p = cv + (size_t)(tid + q*NTHR)*3;
          sx += cld(p); sy += cld(p+1); sz += cld(p+2);
        } else if (uu == T){
          int pos = atomicAdd(&su.u.sa.tieCnt, 1);
          if (pos < 256) su.u.sa.tieIdx[pos] = tid + q*NTHR;
        }
      }
      __syncthreads();
      sx = block_sum(sx, su.u.sa.red);
      sy = block_sum(sy, su.u.sa.red);
      sz = block_sum(sz, su.u.sa.red);
      if (tid==0){
        int mm = su.u.sa.tieCnt < 256 ? su.u.sa.tieCnt : 256;
        for (int tt=0; tt<kneed; tt++){
          int best=-1, bi=0x7fffffff;
          for (int q=0;q<mm;q++){ int v = su.u.sa.tieIdx[q]; if (v < bi){ bi=v; best=q; } }
          if (best >= 0){
            su.u.sa.tieIdx[best] = 0x7fffffff;
            const float* p = cv + (size_t)bi*3;
            sx += cld(p); sy += cld(p+1); sz += cld(p+2);
          }
        }
        cst(&centerb[16 + b*3 + 0], sx/KSEL - cx);
        cst(&centerb[16 + b*3 + 1], sy/KSEL - cy);
        cst(&centerb[16 + b*3 + 2], sz/KSEL - cz);
      }
    } else if (t == 0 && blk < 68){
      /* dir0: canvas[0..N0) -> gt. Both stable since P0. 64 blocks. */
      int rem = blk - 4;
      int b = rem >> 4, l = rem & 15, xb = l >> 2, yb = l & 3;
      chamfer_tile<2>(canvas + (size_t)b*NMAX*3, gt + ((size_t)b*N0 + yb*1024)*3,
                      minAB + b*N0, N0, xb*1024, 1024, true, false,
                      su.u.ch.sy0, su.u.ch.sy1, su.u.ch.sy2, su.u.ch.sny, tid);
    } else if (t >= 1 && blk < 20){
      /* dir2 incremental: new points of step t-1 -> gt. 16 blocks. */
      int rem = blk - 4;
      int b = rem >> 2, yb = rem & 3;
      chamfer_tile<3>(canvas + ((size_t)b*NMAX + N0 + (size_t)(t-1)*NEWP)*3,
                      gt + ((size_t)b*N0 + yb*1024)*3,
                      minCD + b*NNEW + (t-1)*NEWP, NEWP, 0, 1024, true, false,
                      su.u.ch.sy0, su.u.ch.sy1, su.u.ch.sy2, su.u.ch.sny, tid);
    }
    gsync();

    /* ---- REF phase: LSTM finish + refine-decode + canvas append
            + fused enc123 of the new points (192 blocks) ---- */
    if (blk < 192){
      int bx = blk >> 6, b = (blk >> 4) & 3, dcg = blk & 15;  /* 3*4*16 */
      float cx = cld(&centerb[b*3+0]), cy = cld(&centerb[b*3+1]), cz = cld(&centerb[b*3+2]);
      float fx = cld(&centerb[16+b*3+0]), fy = cld(&centerb[16+b*3+1]), fz = cld(&centerb[16+b*3+2]);
      {
        int o = tid;
        float gg = cld(&gpre[b*512 + o]);
        gg += cx*wih[(size_t)256*512+o] + cy*wih[(size_t)257*512+o] + cz*wih[(size_t)258*512+o];
        gg += fx*wih[(size_t)259*512+o] + fy*wih[(size_t)260*512+o] + fz*wih[(size_t)261*512+o];
        su.u.re.sG[o] = gg;
      }
      __syncthreads();
      if (tid < HD){
        float gi=su.u.re.sG[tid], gf=su.u.re.sG[128+tid], gg2=su.u.re.sG[256+tid], go=su.u.re.sG[384+tid];
        float cn = sigm(gf)*cld(&c_in[b*HD+tid]) + sigm(gi)*tanhf(gg2);
        float hn = sigm(go)*tanhf(cn);
        su.u.re.sH[tid] = hn;
        if (bx==0 && dcg==0){ cst(&c_out[b*HD+tid], cn); cst(&h_out[b*HD+tid], hn); }
      }
      __syncthreads();
      if (tid < HD){
        float a = rb1[tid];
        for (int k=0;k<HD;k++) a += su.u.re.sH[k]*rw1[k*HD + tid];
        su.u.re.sRf[tid] = fmaxf(a, 0.f);
      }
      __syncthreads();
      int i = bx*NTHR + tid;
      bool act = i < NEWP;
      int ic = act ? i : 0;
      float a0 = rb2[3*ic], a1 = rb2[3*ic+1], a2 = rb2[3*ic+2];
      for (int k=0;k<HD;k++){
        const float* wv = rw2 + (size_t)k*(NEWP*3) + 3*ic;
        float hk = su.u.re.sRf[k];
        a0 = fmaf(hk, wv[0], a0); a1 = fmaf(hk, wv[1], a1); a2 = fmaf(hk, wv[2], a2);
      }
      float p0 = fmaf(a0, 0.02f, cx), p1 = fmaf(a1, 0.02f, cy), p2 = fmaf(a2, 0.02f, cz);
      if (act && dcg==0){
        float* cp = canvas + ((size_t)b*NMAX + N + i)*3;
        cst(cp+0, p0); cst(cp+1, p1); cst(cp+2, p2);
      }
      if (t < NSTEPS-1){
        enc123_point<1>(p0, p1, p2, dcg*16, w1, b1, w2, b2, w3, b3,
                        act, &gmax[b*GD], tid);
      }
    }
    gsync();
  }

  /* ============ final chamfer: dir1 (128 blks), dir3 (96), dir2-last (16) ==== */
  {
    if (blk < 128){
      int b = blk >> 5, l = blk & 31, xb = l >> 4, yb = l & 15;
      int tn = min(1024, NMAX - yb*1024);
      chamfer_tile<4>(gt + (size_t)b*N0*3, canvas + ((size_t)b*NMAX + yb*1024)*3,
                      minAB + BB*N0 + b*N0, N0, xb*2048, tn, false, true,
                      su.u.ch.sy0, su.u.ch.sy1, su.u.ch.sy2, su.u.ch.sny, tid);
    } else if (blk < 224){
      int rem = blk - 128;
      int b = rem/24, l = rem%24, xb = l/12, yb = l%12;
      int tn = min(1024, NNEW - yb*1024);
      chamfer_tile<4>(gt + (size_t)b*N0*3, canvas + ((size_t)b*NMAX + N0 + yb*1024)*3,
                      minCD + BB*NNEW + b*N0, N0, xb*2048, tn, false, true,
                      su.u.ch.sy0, su.u.ch.sy1, su.u.ch.sy2, su.u.ch.sny, tid);
    } else if (blk < 240){
      int rem = blk - 224;
      int b = rem >> 2, yb = rem & 3;
      chamfer_tile<3>(canvas + ((size_t)b*NMAX + N0 + (size_t)(NSTEPS-1)*NEWP)*3,
                      gt + ((size_t)b*N0 + yb*1024)*3,
                      minCD + b*NNEW + (NSTEPS-1)*NEWP, NEWP, 0, 1024, true, false,
                      su.u.ch.sy0, su.u.ch.sy1, su.u.ch.sy2, su.u.ch.sny, tid);
    }
  }
  gsync();

  /* ============ reduce (blocks 0..15) ============ */
  if (blk < 16){
    int s = blk, dir = s>>2, b = s&3;
    const unsigned* mp; int len;
    if (dir==0){      mp=minAB + b*N0;            len=N0; }
    else if (dir==1){ mp=minAB + BB*N0 + b*N0;    len=N0; }
    else if (dir==2){ mp=minCD + b*NNEW;          len=NNEW; }
    else {            mp=minCD + BB*NNEW + b*N0;  len=N0; }
    float v = 0.f;
    int i = tid;
    for (; i + 3*NTHR < len; i += 4*NTHR){
      unsigned u0=culd(mp+i), u1=culd(mp+i+NTHR), u2=culd(mp+i+2*NTHR), u3=culd(mp+i+3*NTHR);
      v += dec_f(u0); v += dec_f(u1); v += dec_f(u2); v += dec_f(u3);
    }
    for (; i < len; i += NTHR) v += dec_f(culd(mp+i));
    v = block_sum(v, su.u.rd.red);
    if (tid==0) cst(&acc[s], v);
  }
  gsync();

  /* ============ finish ============ */
  if (blk == 0 && tid == 0){
    float cd1 = 0.f, cd2 = 0.f;
    for (int b=0;b<BB;b++) cd1 += cld(&acc[b])/(float)N0 + cld(&acc[4+b])/(float)N0;
    for (int b=0;b<BB;b++) cd2 += cld(&acc[8+b])/(float)NNEW + cld(&acc[12+b])/(float)N0;
    out[0] = 0.1f*(cd1/BB) + 1.0f*(cd2/BB);
  }
}

extern "C" void kernel_launch(void* const* d_in, const int* in_sizes, int n_in,
                              void* d_out, int out_size, void* d_ws, size_t ws_size,
                              hipStream_t stream) {
  (void)in_sizes; (void)n_in; (void)out_size; (void)ws_size;
  const float* points   = (const float*)d_in[0];
  const float* gt       = (const float*)d_in[1];
  const float* enc_w1   = (const float*)d_in[2];
  const float* enc_b1   = (const float*)d_in[3];
  const float* enc_w2   = (const float*)d_in[4];
  const float* enc_b2   = (const float*)d_in[5];
  const float* enc_w3   = (const float*)d_in[6];
  const float* enc_b3   = (const float*)d_in[7];
  const float* att_w1   = (const float*)d_in[8];
  const float* att_b1   = (const float*)d_in[9];
  const float* att_w2   = (const float*)d_in[10];
  const float* att_b2   = (const float*)d_in[11];
  const float* lstm_wih = (const float*)d_in[12];
  const float* lstm_whh = (const float*)d_in[13];
  const float* lstm_bih = (const float*)d_in[14];
  const float* lstm_bhh = (const float*)d_in[15];
  const float* ref_w1   = (const float*)d_in[16];
  const float* ref_b1   = (const float*)d_in[17];
  const float* ref_w2   = (const float*)d_in[18];
  const float* ref_b2   = (const float*)d_in[19];
  float* out = (float*)d_out;
  float* ws  = (float*)d_ws;

  mega_kernel<<<dim3(NBLK), NTHR, 0, stream>>>(
      points, gt,
      enc_w1, enc_b1, enc_w2, enc_b2, enc_w3, enc_b3,
      att_w1, att_b1, att_w2, att_b2,
      lstm_wih, lstm_whh, lstm_bih, lstm_bhh,
      ref_w1, ref_b1, ref_w2, ref_b2,
      out, ws);
}

// Round 4
// 2000.380 us; speedup vs baseline: 2.0767x; 2.0767x over previous
//
#include <hip/hip_runtime.h>
#include <math.h>

#define BB 4
#define N0 4096
#define NEWP 1152
#define GD 256
#define HD 128
#define KSEL 64
#define NSTEPS 10
#define NMAX (N0 + NSTEPS*NEWP)   /* 15616 */
#define NNEW (NSTEPS*NEWP)        /* 11520 */

#define NBLK 256
#define NTHR 512

/* ---- workspace layout (float offsets) ---- */
#define OFF_CANVAS 0
#define OFF_MINAB  (OFF_CANVAS + BB*NMAX*3)
#define OFF_MINCD  (OFF_MINAB + 2*BB*N0)
#define OFF_GMAX   (OFF_MINCD + BB*NNEW + BB*N0)
#define OFF_H      (OFF_GMAX + BB*GD)
#define OFF_C      (OFF_H + 2*BB*HD)
#define OFF_ACC    (OFF_C + 2*BB*HD)
#define OFF_CENTER (OFF_ACC + 16)
#define OFF_PART   (OFF_CENTER + 32)
#define OFF_GPRE   (OFF_PART + BB*32*8)      /* 4*512 gate partials */

#define AGT __HIP_MEMORY_SCOPE_AGENT

/* coherent (cache-bypassing, IF-coherence-point) accessors for cross-block
   data. Weights/inputs keep normal cached loads. */
__device__ __forceinline__ float cld(const float* p){
  return __hip_atomic_load((float*)p, __ATOMIC_RELAXED, AGT);
}
__device__ __forceinline__ void cst(float* p, float v){
  __hip_atomic_store(p, v, __ATOMIC_RELAXED, AGT);
}
__device__ __forceinline__ unsigned culd(const unsigned* p){
  return __hip_atomic_load((unsigned*)p, __ATOMIC_RELAXED, AGT);
}
__device__ __forceinline__ void cust(unsigned* p, unsigned v){
  __hip_atomic_store(p, v, __ATOMIC_RELAXED, AGT);
}
__device__ __forceinline__ float ldc(const float* p, bool coh){
  return coh ? cld(p) : *p;
}

__device__ __forceinline__ unsigned enc_f(float f){
  unsigned u = __float_as_uint(f);
  return (u & 0x80000000u) ? ~u : (u | 0x80000000u);
}
__device__ __forceinline__ float dec_f(unsigned e){
  unsigned u = (e & 0x80000000u) ? (e & 0x7fffffffu) : ~e;
  return __uint_as_float(u);
}
__device__ __forceinline__ float sigm(float x){ return 1.f/(1.f+expf(-x)); }

__device__ __forceinline__ float block_sum(float v, volatile float* red){
#pragma unroll
  for (int s=32;s>0;s>>=1) v += __shfl_down(v, s, 64);
  int lane = threadIdx.x & 63, w = threadIdx.x >> 6, nw = blockDim.x >> 6;
  __syncthreads();
  if (lane==0) red[w] = v;
  __syncthreads();
  if (w==0){
    float x = (lane < nw) ? red[lane] : 0.f;
#pragma unroll
    for (int s=8;s>0;s>>=1) x += __shfl_down(x, s, 64);
    if (lane==0) red[0] = x;
  }
  __syncthreads();
  float r = red[0];
  __syncthreads();
  return r;
}
__device__ __forceinline__ float block_max(float v, volatile float* red){
#pragma unroll
  for (int s=32;s>0;s>>=1) v = fmaxf(v, __shfl_down(v, s, 64));
  int lane = threadIdx.x & 63, w = threadIdx.x >> 6, nw = blockDim.x >> 6;
  __syncthreads();
  if (lane==0) red[w] = v;
  __syncthreads();
  if (w==0){
    float x = (lane < nw) ? red[lane] : -3.4e38f;
#pragma unroll
    for (int s=8;s>0;s>>=1) x = fmaxf(x, __shfl_down(x, s, 64));
    if (lane==0) red[0] = x;
  }
  __syncthreads();
  float r = red[0];
  __syncthreads();
  return r;
}

/* ---- fence-free grid barrier: 2-level monotonic arrive/spin.
   s_sleep(32) backoff: poll period ~0.85us -> spin fetch ~19 GB/s
   (was s_sleep(2): ~300 GB/s of spin traffic saturating the fabric). ---- */
__device__ __align__(128) unsigned g_grp[256];   /* 8 counters, stride 32 */
__device__ __align__(128) unsigned g_root;
__device__ __align__(128) unsigned g_gen;

__device__ __forceinline__ void gsync(){
  __syncthreads();
  if (threadIdx.x == 0){
    unsigned snap = __hip_atomic_load(&g_gen, __ATOMIC_RELAXED, AGT);
    asm volatile("" ::: "memory");
    int g = blockIdx.x >> 5;
    unsigned od = __hip_atomic_fetch_add(&g_grp[g*32], 1u, __ATOMIC_RELAXED, AGT);
    bool done = false;
    if ((od & 31u) == 31u){
      unsigned rd = __hip_atomic_fetch_add(&g_root, 1u, __ATOMIC_RELAXED, AGT);
      if ((rd & 7u) == 7u){
        __hip_atomic_fetch_add(&g_gen, 1u, __ATOMIC_RELAXED, AGT);
        done = true;
      }
    }
    if (!done){
      while (__hip_atomic_load(&g_gen, __ATOMIC_RELAXED, AGT) == snap)
        __builtin_amdgcn_s_sleep(32);
    }
    asm volatile("" ::: "memory");
  }
  __syncthreads();
}

/* one 16KB shared-memory arena, aliased per phase */
struct alignas(16) SU {
  union {
    struct { float sy0[1024], sy1[1024], sy2[1024], sny[1024]; } ch;
    struct { float sBatt[128]; float sGH[GD+HD]; float red[16]; } sl;
    struct { float red[16]; float sC[3]; unsigned cbufA[2][8]; unsigned cbufB[2][8];
             int tieCnt; int tieIdx[256]; } sa;
    struct { float sG[512]; float sH[HD]; float sRf[HD]; } re;
    struct { float red[16]; } rd;
  } u;
};

/* fused enc1->enc2->enc3 for one point, NC 16-wide d-chunks at d0.
   SPILL-FREE: each f2_k is computed as a scalar (64 fma from f1) and
   immediately folded into the accd accumulators -- no f2 array. Live set:
   f1[64] + accd[NC*16] + temps (~100 regs for NC=2). Summation orders are
   bitwise-identical to the reference (f2: j=0..63; f3: k=0..127). */
template<int NC>
__device__ __forceinline__ void enc123_point(
    float p0, float p1, float p2, int d0,
    const float* __restrict__ w1, const float* __restrict__ b1,
    const float* __restrict__ w2, const float* __restrict__ b2,
    const float* __restrict__ w3, const float* __restrict__ b3,
    bool act, unsigned* gmaxrow, int tid)
{
  float f1[64];
#pragma unroll
  for (int j=0;j<64;j++)
    f1[j] = fmaxf(0.f, b1[j] + p0*w1[j] + p1*w1[64+j] + p2*w1[128+j]);
  float accd[NC*16];
#pragma unroll
  for (int c=0;c<NC*16;c++) accd[c] = b3[d0 + c];
#pragma unroll 2
  for (int k=0;k<128;k++){
    float s = b2[k];
#pragma unroll
    for (int j=0;j<64;j++) s = fmaf(f1[j], w2[j*128+k], s);
    float fv = fmaxf(s, 0.f);
    const float* wr = w3 + (size_t)k*256 + d0;
#pragma unroll
    for (int c=0;c<NC*16;c++) accd[c] = fmaf(fv, wr[c], accd[c]);
  }
#pragma unroll
  for (int c=0;c<NC*16;c++){
    float v = act ? accd[c] : -3.4e38f;
#pragma unroll
    for (int s2=32;s2>0;s2>>=1) v = fmaxf(v, __shfl_down(v, s2, 64));
    if ((tid & 63) == 0) atomicMax(&gmaxrow[d0 + c], enc_f(v));
  }
}

/* one chamfer tile: min over a staged Y slab [tn pts] for QN X-chunks */
template<int QN>
__device__ __forceinline__ void chamfer_tile(
    const float* X, const float* Y, unsigned* mp,
    int Nx, int xbase, int tn, bool xcv, bool ycv,
    float* sy0, float* sy1, float* sy2, float* sny, int tid)
{
  for (int tt=tid; tt<tn; tt+=NTHR){
    const float* yp = Y + (size_t)tt*3;
    float y0=ldc(yp,ycv), y1=ldc(yp+1,ycv), y2=ldc(yp+2,ycv);
    sy0[tt]=-2.f*y0; sy1[tt]=-2.f*y1; sy2[tt]=-2.f*y2;
    sny[tt]=y0*y0+y1*y1+y2*y2;
  }
  __syncthreads();
  float X0[QN],X1[QN],X2[QN],NXr[QN],MN[QN]; int XI[QN]; bool VA[QN];
#pragma unroll
  for (int q=0;q<QN;q++){
    int x = xbase + q*NTHR + tid;
    VA[q] = x < Nx;
    int xc = VA[q] ? x : 0;
    const float* xp = X + (size_t)xc*3;
    X0[q]=ldc(xp,xcv); X1[q]=ldc(xp+1,xcv); X2[q]=ldc(xp+2,xcv);
    NXr[q] = X0[q]*X0[q] + X1[q]*X1[q] + X2[q]*X2[q];
    MN[q] = 3.4e38f; XI[q] = xc;
  }
  const float4* v0 = (const float4*)sy0;
  const float4* v1 = (const float4*)sy1;
  const float4* v2 = (const float4*)sy2;
  const float4* vn = (const float4*)sny;
  int j4n = tn >> 2;
  for (int j=0;j<j4n;j++){
    float4 a0 = v0[j], a1 = v1[j], a2 = v2[j], an = vn[j];
#pragma unroll
    for (int e=0;e<4;e++){
      float y0 = ((const float*)&a0)[e];
      float y1 = ((const float*)&a1)[e];
      float y2 = ((const float*)&a2)[e];
      float ny = ((const float*)&an)[e];
#pragma unroll
      for (int q=0;q<QN;q++){
        float d = fmaf(X0[q], y0, fmaf(X1[q], y1, fmaf(X2[q], y2, ny)));
        MN[q] = fminf(MN[q], d);
      }
    }
  }
  for (int j=j4n*4; j<tn; j++){
    float y0=sy0[j], y1=sy1[j], y2=sy2[j], ny=sny[j];
#pragma unroll
    for (int q=0;q<QN;q++){
      float d = fmaf(X0[q], y0, fmaf(X1[q], y1, fmaf(X2[q], y2, ny)));
      MN[q] = fminf(MN[q], d);
    }
  }
#pragma unroll
  for (int q=0;q<QN;q++)
    if (VA[q]) atomicMin(&mp[XI[q]], enc_f(MN[q] + NXr[q]));
}

__global__ __attribute__((amdgpu_flat_work_group_size(NTHR,NTHR), amdgpu_waves_per_eu(2,2)))
void mega_kernel(
    const float* __restrict__ points, const float* __restrict__ gt,
    const float* __restrict__ w1,  const float* __restrict__ b1,
    const float* __restrict__ w2,  const float* __restrict__ b2,
    const float* __restrict__ w3,  const float* __restrict__ b3,
    const float* __restrict__ aw1, const float* __restrict__ ab1,
    const float* __restrict__ aw2, const float* __restrict__ ab2,
    const float* __restrict__ wih, const float* __restrict__ whh,
    const float* __restrict__ bih, const float* __restrict__ bhh,
    const float* __restrict__ rw1, const float* __restrict__ rb1,
    const float* __restrict__ rw2, const float* __restrict__ rb2,
    float* __restrict__ out, float* __restrict__ ws)
{
  __shared__ SU su;
  const int tid = threadIdx.x;
  const int blk = blockIdx.x;

  float* canvas   = ws + OFF_CANVAS;
  unsigned* minAB = (unsigned*)(ws + OFF_MINAB);
  unsigned* minCD = (unsigned*)(ws + OFF_MINCD);
  unsigned* gmax  = (unsigned*)(ws + OFF_GMAX);
  float* hb       = ws + OFF_H;
  float* cb       = ws + OFF_C;
  float* acc      = ws + OFF_ACC;
  float* centerb  = ws + OFF_CENTER;
  float* partb    = ws + OFF_PART;
  float* gpre     = ws + OFF_GPRE;

  /* ============ P0: init ============ */
  {
    int gid = blk*NTHR + tid;
    if (gid < BB*N0*3){
      int b = gid/(N0*3), r = gid - b*(N0*3);
      cst(&canvas[(size_t)b*NMAX*3 + r], points[gid]);
    }
    if (gid < 2*BB*N0) cust(&minAB[gid], 0xFFFFFFFFu);
    if (gid < BB*NNEW + BB*N0) cust(&minCD[gid], 0xFFFFFFFFu);
    if (gid < BB*GD) cust(&gmax[gid], 0u);
    if (gid < 2*BB*HD){ cst(&hb[gid], 0.f); cst(&cb[gid], 0.f); }
  }
  gsync();

  /* ============ P1: fused enc123 + max-pool of the 16384 initial points.
     256 blocks = 32 point-groups x 8 d-groups (32 dims each). ============ */
  {
    int ptg = blk >> 3, dcg = blk & 7;
    int gp = ptg*NTHR + tid;           /* 0..16383 */
    int b  = gp >> 12;
    const float* p = points + (size_t)gp*3;
    float p0 = p[0], p1 = p[1], p2 = p[2];
    enc123_point<2>(p0, p1, p2, dcg*32, w1, b1, w2, b2, w3, b3,
                    true, &gmax[b*GD], tid);
  }
  gsync();

  /* ============ 10-step loop ============ */
  for (int t=0; t<NSTEPS; t++){
    int N   = N0 + t*NEWP;
    int nch = (N + 511) >> 9;
    float* h_in  = hb + (t&1)*BB*HD;
    float* h_out = hb + ((t+1)&1)*BB*HD;
    float* c_in  = cb + (t&1)*BB*HD;
    float* c_out = cb + ((t+1)&1)*BB*HD;

    /* ---- SL phase: attention partials (blocks 0..4nch-1)
            + LSTM gate precompute (blocks 252..255, one per b) ---- */
    if (blk < 4*nch){
      int b = blk / nch, ch = blk - b*nch;
      if (tid < GD+HD)
        su.u.sl.sGH[tid] = (tid < GD) ? dec_f(culd(&gmax[b*GD + tid]))
                                      : cld(&h_in[b*HD + (tid-GD)]);
      __syncthreads();
      if (tid < 128){
        float a = ab1[tid];
        for (int k=0;k<GD+HD;k++) a += su.u.sl.sGH[k] * aw1[(3+k)*128 + tid];
        su.u.sl.sBatt[tid] = a;
      }
      __syncthreads();
      int i = ch*512 + tid;
      bool act = i < N;
      float p0=0.f,p1=0.f,p2=0.f,s=-3.4e38f;
      if (act){
        const float* pp = canvas + (size_t)(b*NMAX + i)*3;
        p0=cld(pp); p1=cld(pp+1); p2=cld(pp+2);
        s = ab2[0];
        for (int j=0;j<128;j++){
          float v = su.u.sl.sBatt[j] + p0*aw1[j] + p1*aw1[128+j] + p2*aw1[256+j];
          s += fmaxf(v, 0.f)*aw2[j];
        }
      }
      float mb = block_max(s, su.u.sl.red);
      float e = act ? expf(s - mb) : 0.f;
      float se = block_sum(e, su.u.sl.red);
      float wx = block_sum(e*p0, su.u.sl.red);
      float wy = block_sum(e*p1, su.u.sl.red);
      float wz = block_sum(e*p2, su.u.sl.red);
      if (tid==0){
        float* pr = partb + (size_t)(b*32 + ch)*8;
        cst(pr+0, mb); cst(pr+1, se); cst(pr+2, wx); cst(pr+3, wy); cst(pr+4, wz);
      }
    } else if (blk >= 252){
      int b = blk - 252;
      if (tid < GD+HD)
        su.u.sl.sGH[tid] = (tid < GD) ? dec_f(culd(&gmax[b*GD + tid]))
                                      : cld(&h_in[b*HD + (tid-GD)]);
      __syncthreads();
      int o = tid;
      float g = bih[o] + bhh[o];
      for (int k=0;k<GD;k++)  g += su.u.sl.sGH[k]    * wih[(size_t)k*512 + o];
      for (int k=0;k<HD;k++)  g += su.u.sl.sGH[GD+k] * whh[(size_t)k*512 + o];
      cst(&gpre[b*512 + o], g);
    }
    gsync();

    /* ---- stepA phase: center+top-K (blocks 0..3)
            + incremental chamfer in otherwise-idle blocks ---- */
    if (blk < 4){
      int b = blk;
      const float* cv = canvas + (size_t)b*NMAX*3;
      int lane = tid & 63, wid = tid >> 6;

      float pm=-3.4e38f, pse=0.f, pwx=0.f, pwy=0.f, pwz=0.f;
      if (tid < nch){
        const float* pp = partb + (size_t)(b*32 + tid)*8;
        pm=cld(pp); pse=cld(pp+1); pwx=cld(pp+2); pwy=cld(pp+3); pwz=cld(pp+4);
      }
      float M = block_max(pm, su.u.sa.red);
      float w = (tid < nch) ? expf(pm - M) : 0.f;
      float se = block_sum(pse*w, su.u.sa.red);
      float wx = block_sum(pwx*w, su.u.sa.red);
      float wy = block_sum(pwy*w, su.u.sa.red);
      float wz = block_sum(pwz*w, su.u.sa.red);
      if (tid==0){ su.u.sa.sC[0]=wx/se; su.u.sa.sC[1]=wy/se; su.u.sa.sC[2]=wz/se; }
      __syncthreads();
      float cx=su.u.sa.sC[0], cy=su.u.sa.sC[1], cz=su.u.sa.sC[2];
      if (tid<3) cst(&centerb[b*3+tid], su.u.sa.sC[tid]);

      unsigned ur[32];
#pragma unroll
      for (int q=0;q<32;q+=8){
        float px[8], py[8], pz[8];
#pragma unroll
        for (int r=0;r<8;r++){
          int i = tid + (q+r)*NTHR;
          int ic2 = (i < N) ? i : 0;
          const float* p = cv + (size_t)ic2*3;
          px[r]=cld(p); py[r]=cld(p+1); pz[r]=cld(p+2);
        }
#pragma unroll
        for (int r=0;r<8;r++){
          int i = tid + (q+r)*NTHR;
          ur[q+r] = 0xFFFFFFFFu;
          if (i < N){
            float dx=px[r]-cx, dy=py[r]-cy, dz=pz[r]-cz;
            ur[q+r] = __float_as_uint(dx*dx + dy*dy + dz*dz);
          }
        }
      }

      unsigned T = 0u;
      int cntBelow = 0;
      int par = 0;
      {
        unsigned cand = 1u<<30;
        unsigned tc = 0;
#pragma unroll
        for (int q=0;q<32;q++) tc += (ur[q] < cand) ? 1u : 0u;
#pragma unroll
        for (int s2=32;s2>0;s2>>=1) tc += __shfl_down(tc, s2, 64);
        if (lane==0) su.u.sa.cbufA[par][wid] = tc;
        __syncthreads();
        unsigned tot = 0;
#pragma unroll
        for (int i2=0;i2<8;i2++) tot += su.u.sa.cbufA[par][i2];
        if ((int)tot < KSEL){ T = cand; cntBelow = (int)tot; }
        par ^= 1;
      }
      for (int bit=29; bit>=1; bit-=2){
        unsigned q1 = 1u<<(bit-1);
        unsigned c1 = T + q1, c2 = T + 2u*q1, c3 = T + 3u*q1;
        unsigned ta = 0, tb = 0;
#pragma unroll
        for (int q=0;q<32;q++){
          unsigned u = ur[q];
          ta += (u < c1 ? 1u : 0u) | (u < c2 ? 0x10000u : 0u);
          tb += (u < c3 ? 1u : 0u);
        }
#pragma unroll
        for (int s2=32;s2>0;s2>>=1){ ta += __shfl_down(ta, s2, 64); tb += __shfl_down(tb, s2, 64); }
        if (lane==0){ su.u.sa.cbufA[par][wid] = ta; su.u.sa.cbufB[par][wid] = tb; }
        __syncthreads();
        unsigned sa2 = 0, sb2 = 0;
#pragma unroll
        for (int i2=0;i2<8;i2++){ sa2 += su.u.sa.cbufA[par][i2]; sb2 += su.u.sa.cbufB[par][i2]; }
        int n1 = (int)(sa2 & 0xFFFFu), n2 = (int)(sa2 >> 16), n3 = (int)sb2;
        if (n3 < KSEL){ T = c3; cntBelow = n3; }
        else if (n2 < KSEL){ T = c2; cntBelow = n2; }
        else if (n1 < KSEL){ T = c1; cntBelow = n1; }
        par ^= 1;
      }
      int kneed = KSEL - cntBelow;

      if (tid==0) su.u.sa.tieCnt = 0;
      __syncthreads();
      float sx=0.f, sy=0.f, sz=0.f;
#pragma unroll
      for (int q=0;q<32;q++){
        unsigned uu = ur[q];
        if (uu < T){
          const float* p = cv + (size_t)(tid + q*NTHR)*3;
          sx += cld(p); sy += cld(p+1); sz += cld(p+2);
        } else if (uu == T){
          int pos = atomicAdd(&su.u.sa.tieCnt, 1);
          if (pos < 256) su.u.sa.tieIdx[pos] = tid + q*NTHR;
        }
      }
      __syncthreads();
      sx = block_sum(sx, su.u.sa.red);
      sy = block_sum(sy, su.u.sa.red);
      sz = block_sum(sz, su.u.sa.red);
      if (tid==0){
        int mm = su.u.sa.tieCnt < 256 ? su.u.sa.tieCnt : 256;
        for (int tt=0; tt<kneed; tt++){
          int best=-1, bi=0x7fffffff;
          for (int q=0;q<mm;q++){ int v = su.u.sa.tieIdx[q]; if (v < bi){ bi=v; best=q; } }
          if (best >= 0){
            su.u.sa.tieIdx[best] = 0x7fffffff;
            const float* p = cv + (size_t)bi*3;
            sx += cld(p); sy += cld(p+1); sz += cld(p+2);
          }
        }
        cst(&centerb[16 + b*3 + 0], sx/KSEL - cx);
        cst(&centerb[16 + b*3 + 1], sy/KSEL - cy);
        cst(&centerb[16 + b*3 + 2], sz/KSEL - cz);
      }
    } else if (t == 0 && blk < 68){
      /* dir0: canvas[0..N0) -> gt. Both stable since P0. 64 blocks. */
      int rem = blk - 4;
      int b = rem >> 4, l = rem & 15, xb = l >> 2, yb = l & 3;
      chamfer_tile<2>(canvas + (size_t)b*NMAX*3, gt + ((size_t)b*N0 + yb*1024)*3,
                      minAB + b*N0, N0, xb*1024, 1024, true, false,
                      su.u.ch.sy0, su.u.ch.sy1, su.u.ch.sy2, su.u.ch.sny, tid);
    } else if (t >= 1 && blk < 20){
      /* dir2 incremental: new points of step t-1 -> gt. 16 blocks. */
      int rem = blk - 4;
      int b = rem >> 2, yb = rem & 3;
      chamfer_tile<3>(canvas + ((size_t)b*NMAX + N0 + (size_t)(t-1)*NEWP)*3,
                      gt + ((size_t)b*N0 + yb*1024)*3,
                      minCD + b*NNEW + (t-1)*NEWP, NEWP, 0, 1024, true, false,
                      su.u.ch.sy0, su.u.ch.sy1, su.u.ch.sy2, su.u.ch.sny, tid);
    }
    gsync();

    /* ---- REF phase: LSTM finish + refine-decode + canvas append
            + fused enc123 of the new points (192 blocks) ---- */
    if (blk < 192){
      int bx = blk >> 6, b = (blk >> 4) & 3, dcg = blk & 15;  /* 3*4*16 */
      float cx = cld(&centerb[b*3+0]), cy = cld(&centerb[b*3+1]), cz = cld(&centerb[b*3+2]);
      float fx = cld(&centerb[16+b*3+0]), fy = cld(&centerb[16+b*3+1]), fz = cld(&centerb[16+b*3+2]);
      {
        int o = tid;
        float gg = cld(&gpre[b*512 + o]);
        gg += cx*wih[(size_t)256*512+o] + cy*wih[(size_t)257*512+o] + cz*wih[(size_t)258*512+o];
        gg += fx*wih[(size_t)259*512+o] + fy*wih[(size_t)260*512+o] + fz*wih[(size_t)261*512+o];
        su.u.re.sG[o] = gg;
      }
      __syncthreads();
      if (tid < HD){
        float gi=su.u.re.sG[tid], gf=su.u.re.sG[128+tid], gg2=su.u.re.sG[256+tid], go=su.u.re.sG[384+tid];
        float cn = sigm(gf)*cld(&c_in[b*HD+tid]) + sigm(gi)*tanhf(gg2);
        float hn = sigm(go)*tanhf(cn);
        su.u.re.sH[tid] = hn;
        if (bx==0 && dcg==0){ cst(&c_out[b*HD+tid], cn); cst(&h_out[b*HD+tid], hn); }
      }
      __syncthreads();
      if (tid < HD){
        float a = rb1[tid];
        for (int k=0;k<HD;k++) a += su.u.re.sH[k]*rw1[k*HD + tid];
        su.u.re.sRf[tid] = fmaxf(a, 0.f);
      }
      __syncthreads();
      int i = bx*NTHR + tid;
      bool act = i < NEWP;
      int ic = act ? i : 0;
      float a0 = rb2[3*ic], a1 = rb2[3*ic+1], a2 = rb2[3*ic+2];
      for (int k=0;k<HD;k++){
        const float* wv = rw2 + (size_t)k*(NEWP*3) + 3*ic;
        float hk = su.u.re.sRf[k];
        a0 = fmaf(hk, wv[0], a0); a1 = fmaf(hk, wv[1], a1); a2 = fmaf(hk, wv[2], a2);
      }
      float p0 = fmaf(a0, 0.02f, cx), p1 = fmaf(a1, 0.02f, cy), p2 = fmaf(a2, 0.02f, cz);
      if (act && dcg==0){
        float* cp = canvas + ((size_t)b*NMAX + N + i)*3;
        cst(cp+0, p0); cst(cp+1, p1); cst(cp+2, p2);
      }
      if (t < NSTEPS-1){
        enc123_point<1>(p0, p1, p2, dcg*16, w1, b1, w2, b2, w3, b3,
                        act, &gmax[b*GD], tid);
      }
    }
    gsync();
  }

  /* ============ final chamfer: dir1 (128 blks), dir3 (96), dir2-last (16) ==== */
  {
    if (blk < 128){
      int b = blk >> 5, l = blk & 31, xb = l >> 4, yb = l & 15;
      int tn = min(1024, NMAX - yb*1024);
      chamfer_tile<4>(gt + (size_t)b*N0*3, canvas + ((size_t)b*NMAX + yb*1024)*3,
                      minAB + BB*N0 + b*N0, N0, xb*2048, tn, false, true,
                      su.u.ch.sy0, su.u.ch.sy1, su.u.ch.sy2, su.u.ch.sny, tid);
    } else if (blk < 224){
      int rem = blk - 128;
      int b = rem/24, l = rem%24, xb = l/12, yb = l%12;
      int tn = min(1024, NNEW - yb*1024);
      chamfer_tile<4>(gt + (size_t)b*N0*3, canvas + ((size_t)b*NMAX + N0 + yb*1024)*3,
                      minCD + BB*NNEW + b*N0, N0, xb*2048, tn, false, true,
                      su.u.ch.sy0, su.u.ch.sy1, su.u.ch.sy2, su.u.ch.sny, tid);
    } else if (blk < 240){
      int rem = blk - 224;
      int b = rem >> 2, yb = rem & 3;
      chamfer_tile<3>(canvas + ((size_t)b*NMAX + N0 + (size_t)(NSTEPS-1)*NEWP)*3,
                      gt + ((size_t)b*N0 + yb*1024)*3,
                      minCD + b*NNEW + (NSTEPS-1)*NEWP, NEWP, 0, 1024, true, false,
                      su.u.ch.sy0, su.u.ch.sy1, su.u.ch.sy2, su.u.ch.sny, tid);
    }
  }
  gsync();

  /* ============ reduce (blocks 0..15) ============ */
  if (blk < 16){
    int s = blk, dir = s>>2, b = s&3;
    const unsigned* mp; int len;
    if (dir==0){      mp=minAB + b*N0;            len=N0; }
    else if (dir==1){ mp=minAB + BB*N0 + b*N0;    len=N0; }
    else if (dir==2){ mp=minCD + b*NNEW;          len=NNEW; }
    else {            mp=minCD + BB*NNEW + b*N0;  len=N0; }
    float v = 0.f;
    int i = tid;
    for (; i + 3*NTHR < len; i += 4*NTHR){
      unsigned u0=culd(mp+i), u1=culd(mp+i+NTHR), u2=culd(mp+i+2*NTHR), u3=culd(mp+i+3*NTHR);
      v += dec_f(u0); v += dec_f(u1); v += dec_f(u2); v += dec_f(u3);
    }
    for (; i < len; i += NTHR) v += dec_f(culd(mp+i));
    v = block_sum(v, su.u.rd.red);
    if (tid==0) cst(&acc[s], v);
  }
  gsync();

  /* ============ finish ============ */
  if (blk == 0 && tid == 0){
    float cd1 = 0.f, cd2 = 0.f;
    for (int b=0;b<BB;b++) cd1 += cld(&acc[b])/(float)N0 + cld(&acc[4+b])/(float)N0;
    for (int b=0;b<BB;b++) cd2 += cld(&acc[8+b])/(float)NNEW + cld(&acc[12+b])/(float)N0;
    out[0] = 0.1f*(cd1/BB) + 1.0f*(cd2/BB);
  }
}

extern "C" void kernel_launch(void* const* d_in, const int* in_sizes, int n_in,
                              void* d_out, int out_size, void* d_ws, size_t ws_size,
                              hipStream_t stream) {
  (void)in_sizes; (void)n_in; (void)out_size; (void)ws_size;
  const float* points   = (const float*)d_in[0];
  const float* gt       = (const float*)d_in[1];
  const float* enc_w1   = (const float*)d_in[2];
  const float* enc_b1   = (const float*)d_in[3];
  const float* enc_w2   = (const float*)d_in[4];
  const float* enc_b2   = (const float*)d_in[5];
  const float* enc_w3   = (const float*)d_in[6];
  const float* enc_b3   = (const float*)d_in[7];
  const float* att_w1   = (const float*)d_in[8];
  const float* att_b1   = (const float*)d_in[9];
  const float* att_w2   = (const float*)d_in[10];
  const float* att_b2   = (const float*)d_in[11];
  const float* lstm_wih = (const float*)d_in[12];
  const float* lstm_whh = (const float*)d_in[13];
  const float* lstm_bih = (const float*)d_in[14];
  const float* lstm_bhh = (const float*)d_in[15];
  const float* ref_w1   = (const float*)d_in[16];
  const float* ref_b1   = (const float*)d_in[17];
  const float* ref_w2   = (const float*)d_in[18];
  const float* ref_b2   = (const float*)d_in[19];
  float* out = (float*)d_out;
  float* ws  = (float*)d_ws;

  mega_kernel<<<dim3(NBLK), NTHR, 0, stream>>>(
      points, gt,
      enc_w1, enc_b1, enc_w2, enc_b2, enc_w3, enc_b3,
      att_w1, att_b1, att_w2, att_b2,
      lstm_wih, lstm_whh, lstm_bih, lstm_bhh,
      ref_w1, ref_b1, ref_w2, ref_b2,
      out, ws);
}